// Round 4
// baseline (585.411 us; speedup 1.0000x reference)
//
#include <hip/hip_runtime.h>
#include <math.h>

// ---------------- wave helpers (wave = 64 lanes) ----------------
__device__ __forceinline__ float wave_max(float v) {
  for (int m = 32; m > 0; m >>= 1) v = fmaxf(v, __shfl_xor(v, m, 64));
  return v;
}
__device__ __forceinline__ float wave_sum(float v) {
  for (int m = 32; m > 0; m >>= 1) v += __shfl_xor(v, m, 64);
  return v;
}
__device__ __forceinline__ int wave_sum_i(int v) {
  for (int m = 32; m > 0; m >>= 1) v += __shfl_xor(v, m, 64);
  return v;
}

// ---------------- Kernel 1: matching + localization loss ----------------
// grid = B, block = 256. Each block handles one batch element.
// Single pass over the G x P IoU matrix: tracks per-prior best gt (first-max
// over g, strict >) and per-gt best prior (first-max over p) simultaneously.
// Forced best_iou=2.0 writes are deferred until all chunks complete so
// best_gt is the pure argmax (matches reference, which never updates best_gt).
__global__ __launch_bounds__(256) void match_kernel(
    const float* __restrict__ priors,   // [P,4] cxcywh
    const float* __restrict__ gt_box,   // [B,G,4] xyxy
    const int* __restrict__ gt_class,   // [B,G]
    const float* __restrict__ loc_p,    // [B,P,4]
    float* __restrict__ best_iou,       // [B,P] ws
    int* __restrict__ best_gt,          // [B,P] ws
    int* __restrict__ class_t,          // [B,P] ws
    int* __restrict__ num_pos_arr,      // [B] ws
    float* __restrict__ loss_l_accum,   // [1] ws (pre-zeroed)
    int* __restrict__ n_total,          // [1] ws (pre-zeroed)
    int P, int G)
{
  const int b = blockIdx.x;
  const int tid = threadIdx.x;
  const int lane = tid & 63;
  const int wv = tid >> 6;

  __shared__ float sgx1[64], sgy1[64], sgx2[64], sgy2[64], sga[64];
  __shared__ int sgtc[64];
  __shared__ int sforce[64];           // per-gt winning prior index
  __shared__ float swv[4][16];
  __shared__ int swi[4][16];
  __shared__ float sredf[4];
  __shared__ int sredi[4];

  for (int g = tid; g < G; g += 256) {
    float x1 = gt_box[((size_t)b * G + g) * 4 + 0];
    float y1 = gt_box[((size_t)b * G + g) * 4 + 1];
    float x2 = gt_box[((size_t)b * G + g) * 4 + 2];
    float y2 = gt_box[((size_t)b * G + g) * 4 + 3];
    sgx1[g] = x1; sgy1[g] = y1; sgx2[g] = x2; sgy2[g] = y2;
    sga[g] = (x2 - x1) * (y2 - y1);
    sgtc[g] = gt_class[(size_t)b * G + g];
  }
  __syncthreads();

  // ---- Fused IoU pass: chunks of 16 g's ----
  for (int g0 = 0; g0 < G; g0 += 16) {
    const int gc = min(16, G - g0);
    float bpv[16]; int bpi[16];
#pragma unroll
    for (int gg = 0; gg < 16; ++gg) { bpv[gg] = -INFINITY; bpi[gg] = 0x7fffffff; }

    for (int p = tid; p < P; p += 256) {
      const size_t ip = (size_t)b * P + p;
      float pcx = priors[p * 4 + 0], pcy = priors[p * 4 + 1];
      float pw = priors[p * 4 + 2], ph = priors[p * 4 + 3];
      float px1 = pcx - pw * 0.5f, py1 = pcy - ph * 0.5f;
      float px2 = pcx + pw * 0.5f, py2 = pcy + ph * 0.5f;
      float pa = (px2 - px1) * (py2 - py1);
      float bv; int bg;
      if (g0 == 0) { bv = -INFINITY; bg = 0; }
      else { bv = best_iou[ip]; bg = best_gt[ip]; }   // carry across chunks
#pragma unroll
      for (int gg = 0; gg < 16; ++gg) {
        if (gg < gc) {
          int g = g0 + gg;
          float ix = fmaxf(fminf(sgx2[g], px2) - fmaxf(sgx1[g], px1), 0.f);
          float iy = fmaxf(fminf(sgy2[g], py2) - fmaxf(sgy1[g], py1), 0.f);
          float inter = ix * iy;
          float ov = inter / (sga[g] + pa - inter);
          if (ov > bv) { bv = ov; bg = g; }            // g ascending: first-max
          if (ov > bpv[gg]) { bpv[gg] = ov; bpi[gg] = p; }  // p ascending: first-max
        }
      }
      best_iou[ip] = bv;
      best_gt[ip] = bg;
    }

    // cross-lane / cross-wave reduce per-gt best prior (tie -> smaller index)
#pragma unroll
    for (int gg = 0; gg < 16; ++gg) {
      if (gg < gc) {
        float v = bpv[gg]; int idx = bpi[gg];
        for (int m = 32; m > 0; m >>= 1) {
          float ov = __shfl_xor(v, m, 64);
          int oi = __shfl_xor(idx, m, 64);
          if (ov > v || (ov == v && oi < idx)) { v = ov; idx = oi; }
        }
        if (lane == 0) { swv[wv][gg] = v; swi[wv][gg] = idx; }
      }
    }
    __syncthreads();
    if (tid < gc) {
      float v = swv[0][tid]; int idx = swi[0][tid];
      for (int w = 1; w < 4; ++w) {
        float ov = swv[w][tid]; int oi = swi[w][tid];
        if (ov > v || (ov == v && oi < idx)) { v = ov; idx = oi; }
      }
      sforce[g0 + tid] = idx;
    }
    __syncthreads();
  }

  // ---- deferred force: each gt's best prior gets best_iou = 2.0 ----
  if (tid < G) {
    int idx = sforce[tid];
    if (idx >= 0 && idx < P) best_iou[(size_t)b * P + idx] = 2.0f;
  }
  __syncthreads();

  // ---- Phase 3: class_t, num_pos, smooth-L1 loc loss ----
  int cnt = 0; float lsum = 0.f;
  for (int p = tid; p < P; p += 256) {
    size_t ip = (size_t)b * P + p;
    float bi = best_iou[ip];
    int bg = best_gt[ip];
    int ct = (bi < 0.5f) ? 0 : (sgtc[bg] + 1);
    class_t[ip] = ct;
    if (ct > 0) {
      cnt++;
      float pcx = priors[p * 4 + 0], pcy = priors[p * 4 + 1];
      float pw = priors[p * 4 + 2], ph = priors[p * 4 + 3];
      float mx1 = sgx1[bg], my1 = sgy1[bg], mx2 = sgx2[bg], my2 = sgy2[bg];
      float tx = ((mx1 + mx2) * 0.5f - pcx) / (pw * 0.1f);
      float ty = ((my1 + my2) * 0.5f - pcy) / (ph * 0.1f);
      float tw = logf((mx2 - mx1) / pw) / 0.2f;
      float th = logf((my2 - my1) / ph) / 0.2f;
      const float* lp = loc_p + ip * 4;
      float t0[4] = {tx, ty, tw, th};
#pragma unroll
      for (int j = 0; j < 4; ++j) {
        float d = fabsf(lp[j] - t0[j]);
        lsum += (d < 1.f) ? 0.5f * d * d : d - 0.5f;
      }
    }
  }
  lsum = wave_sum(lsum);
  cnt = wave_sum_i(cnt);
  if (lane == 0) { sredf[wv] = lsum; sredi[wv] = cnt; }
  __syncthreads();
  if (tid == 0) {
    float ls = sredf[0] + sredf[1] + sredf[2] + sredf[3];
    int c = sredi[0] + sredi[1] + sredi[2] + sredi[3];
    num_pos_arr[b] = c;
    atomicAdd(n_total, c);
    atomicAdd(loss_l_accum, ls);
  }
}

// ---------------- Kernel 2: per-prior CE + loss_gt ----------------
// 16 rows per block, staged via float4 into LDS; one wave handles 4 rows.
#define ROWS_PB 16
#define MAXC 128
__global__ __launch_bounds__(256) void ce_kernel(
    const float* __restrict__ class_p,  // [nrows, C]
    const int* __restrict__ class_t,    // [nrows]
    float* __restrict__ loss_gt,        // [nrows]
    float* __restrict__ loss_c_accum,   // [1]
    int C, long long nrows)
{
  __shared__ float4 srow4[ROWS_PB * MAXC / 4];
  float* srow = (float*)srow4;
  __shared__ float sposce[4];

  long long row0 = (long long)blockIdx.x * ROWS_PB;
  int rows_valid = (int)(nrows - row0 < ROWS_PB ? nrows - row0 : ROWS_PB);
  int totalf = rows_valid * C;
  const float* gsrc = class_p + row0 * C;
  int total4 = totalf >> 2;
  const float4* gsrc4 = (const float4*)gsrc;
  for (int i = threadIdx.x; i < total4; i += 256) srow4[i] = gsrc4[i];
  for (int i = (total4 << 2) + threadIdx.x; i < totalf; i += 256) srow[i] = gsrc[i];
  __syncthreads();

  const int wv = threadIdx.x >> 6;
  const int lane = threadIdx.x & 63;
  float posce = 0.f;
#pragma unroll
  for (int rr = 0; rr < ROWS_PB / 4; ++rr) {
    int r = wv * (ROWS_PB / 4) + rr;
    if (r < rows_valid) {
      const float* x = srow + r * C;
      float m = -INFINITY;
      for (int c = lane; c < C; c += 64) m = fmaxf(m, x[c]);
      m = wave_max(m);
      float s = 0.f;
      for (int c = lane; c < C; c += 64) s += expf(x[c] - m);
      s = wave_sum(s);
      if (lane == 0) {
        long long row = row0 + r;
        int ct = class_t[row];
        float ce = m + logf(s) - x[ct];
        if (ct > 0) { loss_gt[row] = 0.f; posce += ce; }
        else        { loss_gt[row] = fmaxf(ce, 0.f); }  // clamp: keeps uint-compare monotone
      }
    }
  }
  posce = wave_sum(posce);
  if (lane == 0) sposce[wv] = posce;
  __syncthreads();
  if (threadIdx.x == 0) {
    float t = sposce[0] + sposce[1] + sposce[2] + sposce[3];
    if (t != 0.f) atomicAdd(loss_c_accum, t);
  }
}

// ---------------- Kernel 3: per-batch sum of top-k loss_gt ----------------
// grid = B. Binary search on float bit pattern (values are >= 0).
// loss_c needs only the SUM of selected CE values; ties at the k-th value
// contribute identically regardless of stable-sort order, so
// sum(top-k) = sum(values > v_k) + v_k * (k - count(> v_k)) is exact.
__global__ __launch_bounds__(256) void topk_kernel(
    const float* __restrict__ loss_gt, const int* __restrict__ num_pos_arr,
    float* __restrict__ loss_c_accum, int P, int negpos_ratio)
{
  extern __shared__ float sv[];
  __shared__ int scnt[4];
  __shared__ float ssumf[4];
  __shared__ int s_total;

  const int b = blockIdx.x;
  const int tid = threadIdx.x;
  const int lane = tid & 63, wv = tid >> 6;
  for (int i = tid; i < P; i += 256) sv[i] = loss_gt[(size_t)b * P + i];
  __syncthreads();
  int np = num_pos_arr[b];
  int k = min(negpos_ratio * np, P - 1);
  if (k <= 0) return;

  unsigned u = 0;
  for (int bit = 30; bit >= 0; --bit) {
    unsigned cand = u | (1u << bit);
    int cnt = 0;
    for (int i = tid; i < P; i += 256) cnt += (__float_as_uint(sv[i]) >= cand) ? 1 : 0;
    cnt = wave_sum_i(cnt);
    if (lane == 0) scnt[wv] = cnt;
    __syncthreads();
    if (tid == 0) s_total = scnt[0] + scnt[1] + scnt[2] + scnt[3];
    __syncthreads();
    if (s_total >= k) u = cand;
  }
  // u == bit pattern of the k-th largest value v_k
  float vk = __uint_as_float(u);
  int cgt = 0; float sgt = 0.f;
  for (int i = tid; i < P; i += 256) {
    float v = sv[i];
    if (__float_as_uint(v) > u) { cgt += 1; sgt += v; }
  }
  cgt = wave_sum_i(cgt);
  sgt = wave_sum(sgt);
  if (lane == 0) { scnt[wv] = cgt; ssumf[wv] = sgt; }
  __syncthreads();
  if (tid == 0) {
    int cg = scnt[0] + scnt[1] + scnt[2] + scnt[3];
    float sg = ssumf[0] + ssumf[1] + ssumf[2] + ssumf[3];
    atomicAdd(loss_c_accum, sg + vk * (float)(k - cg));
  }
}

// ---------------- Kernel 4: finalize ----------------
__global__ void finalize_kernel(const float* __restrict__ lla,
                                const float* __restrict__ lca,
                                const int* __restrict__ nt,
                                float* __restrict__ out)
{
  if (threadIdx.x == 0 && blockIdx.x == 0) {
    float N = (float)(*nt);
    out[0] = lla[0] / N;
    out[1] = lca[0] / N;
  }
}

extern "C" void kernel_launch(void* const* d_in, const int* in_sizes, int n_in,
                              void* d_out, int out_size, void* d_ws, size_t ws_size,
                              hipStream_t stream) {
  const float* loc_p   = (const float*)d_in[0];
  const float* class_p = (const float*)d_in[1];
  const float* priors  = (const float*)d_in[2];
  const float* gt_box  = (const float*)d_in[3];
  const int*   gt_cls  = (const int*)d_in[4];

  const int P = in_sizes[2] / 4;
  const int B = in_sizes[0] / (4 * P);
  const int C = (int)((long long)in_sizes[1] / ((long long)B * P));
  const int G = in_sizes[4] / B;
  const long long BP = (long long)B * P;

  char* w = (char*)d_ws;
  float* best_iou = (float*)w; w += BP * 4;
  int*   bst_gt   = (int*)w;   w += BP * 4;
  int*   cls_t    = (int*)w;   w += BP * 4;
  float* loss_gt  = (float*)w; w += BP * 4;
  int*   num_pos  = (int*)w;   w += (size_t)B * 4;
  float* lla      = (float*)w; w += 4;
  float* lca      = (float*)w; w += 4;
  int*   ntot     = (int*)w;   w += 4;

  hipMemsetAsync(lla, 0, 12, stream);  // lla, lca, ntot

  match_kernel<<<B, 256, 0, stream>>>(priors, gt_box, gt_cls, loc_p,
      best_iou, bst_gt, cls_t, num_pos, lla, ntot, P, G);

  const long long nrows = BP;
  const int nblocks = (int)((nrows + ROWS_PB - 1) / ROWS_PB);
  ce_kernel<<<nblocks, 256, 0, stream>>>(class_p, cls_t, loss_gt, lca, C, nrows);

  topk_kernel<<<B, 256, (size_t)P * sizeof(float), stream>>>(
      loss_gt, num_pos, lca, P, 3);

  finalize_kernel<<<1, 1, 0, stream>>>(lla, lca, ntot, (float*)d_out);
}

// Round 5
// 416.281 us; speedup vs baseline: 1.4063x; 1.4063x over previous
//
#include <hip/hip_runtime.h>
#include <math.h>

#define SPLIT 16

// ---------------- wave helpers (wave = 64 lanes) ----------------
__device__ __forceinline__ float wave_sum(float v) {
  for (int m = 32; m > 0; m >>= 1) v += __shfl_xor(v, m, 64);
  return v;
}
__device__ __forceinline__ int wave_sum_i(int v) {
  for (int m = 32; m > 0; m >>= 1) v += __shfl_xor(v, m, 64);
  return v;
}
__device__ __forceinline__ unsigned long long wave_max_key(unsigned long long k) {
  for (int m = 32; m > 0; m >>= 1) {
    unsigned lo = (unsigned)k, hi = (unsigned)(k >> 32);
    lo = __shfl_xor(lo, m, 64); hi = __shfl_xor(hi, m, 64);
    unsigned long long o = ((unsigned long long)hi << 32) | lo;
    if (o > k) k = o;
  }
  return k;
}

// ---------------- M1: per-prior best gt + per-gt best prior (atomicMax) ----
// grid = (SPLIT, B), block = 256. key = (iou_bits<<32)|(0x7FFFFFFF-p):
// iou>=0 so float bits are order-monotone; ties -> smaller p wins (first-max).
__global__ __launch_bounds__(256) void match1_kernel(
    const float* __restrict__ priors, const float* __restrict__ gt_box,
    float* __restrict__ best_iou, int* __restrict__ best_gt,
    unsigned long long* __restrict__ gt_best,   // [B,G], pre-zeroed
    int P, int G, int chunk)
{
  const int b = blockIdx.y;
  const int p0 = blockIdx.x * chunk;
  const int p1 = min(p0 + chunk, P);
  const int tid = threadIdx.x, lane = tid & 63;

  __shared__ float sgx1[64], sgy1[64], sgx2[64], sgy2[64], sga[64];
  for (int g = tid; g < G; g += 256) {
    float x1 = gt_box[((size_t)b * G + g) * 4 + 0];
    float y1 = gt_box[((size_t)b * G + g) * 4 + 1];
    float x2 = gt_box[((size_t)b * G + g) * 4 + 2];
    float y2 = gt_box[((size_t)b * G + g) * 4 + 3];
    sgx1[g] = x1; sgy1[g] = y1; sgx2[g] = x2; sgy2[g] = y2;
    sga[g] = (x2 - x1) * (y2 - y1);
  }
  __syncthreads();

  for (int g0 = 0; g0 < G; g0 += 16) {
    const int gc = min(16, G - g0);
    unsigned long long bkey[16];
#pragma unroll
    for (int gg = 0; gg < 16; ++gg) bkey[gg] = 0ull;

    for (int p = p0 + tid; p < p1; p += 256) {
      const size_t ip = (size_t)b * P + p;
      float pcx = priors[p * 4 + 0], pcy = priors[p * 4 + 1];
      float pw = priors[p * 4 + 2], ph = priors[p * 4 + 3];
      float px1 = pcx - pw * 0.5f, py1 = pcy - ph * 0.5f;
      float px2 = pcx + pw * 0.5f, py2 = pcy + ph * 0.5f;
      float pa = (px2 - px1) * (py2 - py1);
      float bv; int bg;
      if (g0 == 0) { bv = -INFINITY; bg = 0; }
      else { bv = best_iou[ip]; bg = best_gt[ip]; }   // carry across chunks
#pragma unroll
      for (int gg = 0; gg < 16; ++gg) {
        if (gg < gc) {
          int g = g0 + gg;
          float ix = fmaxf(fminf(sgx2[g], px2) - fmaxf(sgx1[g], px1), 0.f);
          float iy = fmaxf(fminf(sgy2[g], py2) - fmaxf(sgy1[g], py1), 0.f);
          float inter = ix * iy;
          float ov = inter / (sga[g] + pa - inter);
          if (ov > bv) { bv = ov; bg = g; }           // g ascending: first-max
          unsigned long long key =
              ((unsigned long long)__float_as_uint(ov) << 32) |
              (unsigned)(0x7FFFFFFF - p);
          if (key > bkey[gg]) bkey[gg] = key;
        }
      }
      best_iou[ip] = bv;
      best_gt[ip] = bg;
    }

#pragma unroll
    for (int gg = 0; gg < 16; ++gg) {
      if (gg < gc) {
        unsigned long long k = wave_max_key(bkey[gg]);
        if (lane == 0 && k)
          atomicMax(&gt_best[(size_t)b * G + g0 + gg], k);
      }
    }
  }
}

// ---------------- M2: force each gt's best prior to iou=2.0 ----------------
__global__ void force_kernel(const unsigned long long* __restrict__ gt_best,
                             float* __restrict__ best_iou, int P, int G)
{
  const int b = blockIdx.x, t = threadIdx.x;
  if (t < G) {
    unsigned long long k = gt_best[(size_t)b * G + t];
    int p = 0x7FFFFFFF - (int)(unsigned)(k & 0xFFFFFFFFu);
    if (p >= 0 && p < P) best_iou[(size_t)b * P + p] = 2.0f;
  }
}

// ---------------- M3: class_t, num_pos, smooth-L1 loc loss ----------------
// grid = (SPLIT, B), block = 256.
__global__ __launch_bounds__(256) void match3_kernel(
    const float* __restrict__ priors, const float* __restrict__ gt_box,
    const int* __restrict__ gt_class, const float* __restrict__ loc_p,
    const float* __restrict__ best_iou, const int* __restrict__ best_gt,
    int* __restrict__ class_t, int* __restrict__ num_pos_arr,
    float* __restrict__ loss_l_accum, int* __restrict__ n_total,
    int P, int G, int chunk)
{
  const int b = blockIdx.y;
  const int p0 = blockIdx.x * chunk;
  const int p1 = min(p0 + chunk, P);
  const int tid = threadIdx.x, lane = tid & 63, wv = tid >> 6;

  __shared__ float sgx1[64], sgy1[64], sgx2[64], sgy2[64];
  __shared__ int sgtc[64];
  __shared__ float sredf[4];
  __shared__ int sredi[4];

  for (int g = tid; g < G; g += 256) {
    sgx1[g] = gt_box[((size_t)b * G + g) * 4 + 0];
    sgy1[g] = gt_box[((size_t)b * G + g) * 4 + 1];
    sgx2[g] = gt_box[((size_t)b * G + g) * 4 + 2];
    sgy2[g] = gt_box[((size_t)b * G + g) * 4 + 3];
    sgtc[g] = gt_class[(size_t)b * G + g];
  }
  __syncthreads();

  int cnt = 0; float lsum = 0.f;
  for (int p = p0 + tid; p < p1; p += 256) {
    const size_t ip = (size_t)b * P + p;
    float bi = best_iou[ip];
    int bg = best_gt[ip];
    int ct = (bi < 0.5f) ? 0 : (sgtc[bg] + 1);
    class_t[ip] = ct;
    if (ct > 0) {
      cnt++;
      float pcx = priors[p * 4 + 0], pcy = priors[p * 4 + 1];
      float pw = priors[p * 4 + 2], ph = priors[p * 4 + 3];
      float mx1 = sgx1[bg], my1 = sgy1[bg], mx2 = sgx2[bg], my2 = sgy2[bg];
      float tx = ((mx1 + mx2) * 0.5f - pcx) / (pw * 0.1f);
      float ty = ((my1 + my2) * 0.5f - pcy) / (ph * 0.1f);
      float tw = logf((mx2 - mx1) / pw) / 0.2f;
      float th = logf((my2 - my1) / ph) / 0.2f;
      const float* lp = loc_p + ip * 4;
      float t0[4] = {tx, ty, tw, th};
#pragma unroll
      for (int j = 0; j < 4; ++j) {
        float d = fabsf(lp[j] - t0[j]);
        lsum += (d < 1.f) ? 0.5f * d * d : d - 0.5f;
      }
    }
  }
  lsum = wave_sum(lsum);
  cnt = wave_sum_i(cnt);
  if (lane == 0) { sredf[wv] = lsum; sredi[wv] = cnt; }
  __syncthreads();
  if (tid == 0) {
    float ls = sredf[0] + sredf[1] + sredf[2] + sredf[3];
    int c = sredi[0] + sredi[1] + sredi[2] + sredi[3];
    if (c) { atomicAdd(&num_pos_arr[b], c); atomicAdd(n_total, c); }
    if (ls != 0.f) atomicAdd(loss_l_accum, ls);
  }
}

// ---------------- Kernel 2: per-prior CE, thread-per-row ----------------
// 128 rows staged via coalesced float4 into LDS; thread t owns row t.
// Zero shuffles in the row reduction. Bank pattern (l*81+c) mod 32:
// 81=17 mod 32, odd => bijective over banks, 2 lanes/bank = conflict-free.
#define CE_ROWS 128
#define CE_MAXC 96
__global__ __launch_bounds__(CE_ROWS) void ce_kernel(
    const float* __restrict__ class_p,  // [nrows, C]
    const int* __restrict__ class_t,    // [nrows]
    float* __restrict__ loss_gt,        // [nrows]
    float* __restrict__ loss_c_accum,   // [1]
    int C, long long nrows)
{
  __shared__ float4 sbuf4[CE_ROWS * CE_MAXC / 4];
  float* srow = (float*)sbuf4;
  __shared__ float sred[CE_ROWS / 64];

  const long long row0 = (long long)blockIdx.x * CE_ROWS;
  const int rows_valid = (int)(nrows - row0 < CE_ROWS ? nrows - row0 : CE_ROWS);
  const int totalf = rows_valid * C;
  const float* gsrc = class_p + row0 * C;
  const int total4 = totalf >> 2;
  const float4* gsrc4 = (const float4*)gsrc;
  for (int i = threadIdx.x; i < total4; i += CE_ROWS) sbuf4[i] = gsrc4[i];
  for (int i = (total4 << 2) + threadIdx.x; i < totalf; i += CE_ROWS) srow[i] = gsrc[i];
  __syncthreads();

  const int t = threadIdx.x, lane = t & 63, wv = t >> 6;
  float pc = 0.f;
  if (t < rows_valid) {
    const float* x = srow + t * C;
    float m = -INFINITY;
    for (int c = 0; c < C; ++c) m = fmaxf(m, x[c]);
    float s = 0.f;
    for (int c = 0; c < C; ++c) s += __expf(x[c] - m);
    const long long row = row0 + t;
    const int ct = class_t[row];
    const float ce = m + __logf(s) - x[ct];
    float lg;
    if (ct > 0) { lg = 0.f; pc = ce; }
    else        { lg = fmaxf(ce, 0.f); }   // clamp keeps uint-compare monotone
    loss_gt[row] = lg;
  }
  pc = wave_sum(pc);
  if (lane == 0) sred[wv] = pc;
  __syncthreads();
  if (t == 0) {
    float s = 0.f;
#pragma unroll
    for (int j = 0; j < CE_ROWS / 64; ++j) s += sred[j];
    if (s != 0.f) atomicAdd(loss_c_accum, s);
  }
}

// ---------------- Kernel 3: per-batch sum of top-k loss_gt ----------------
// grid = B, block = 1024 (16 waves). Binary search on float bit pattern.
// sum(top-k) = sum(v > v_k) + v_k * (k - count(> v_k)) — exact under ties.
__global__ __launch_bounds__(1024) void topk_kernel(
    const float* __restrict__ loss_gt, const int* __restrict__ num_pos_arr,
    float* __restrict__ loss_c_accum, int P, int negpos_ratio)
{
  extern __shared__ float sv[];
  __shared__ int scnt[16];
  __shared__ float ssum[16];

  const int b = blockIdx.x;
  const int tid = threadIdx.x;
  const int lane = tid & 63, wv = tid >> 6;
  for (int i = tid; i < P; i += 1024) sv[i] = loss_gt[(size_t)b * P + i];
  __syncthreads();
  const int np = num_pos_arr[b];
  const int k = min(negpos_ratio * np, P - 1);
  if (k <= 0) return;

  unsigned u = 0;
  for (int bit = 30; bit >= 0; --bit) {
    unsigned cand = u | (1u << bit);
    int cnt = 0;
    for (int i = tid; i < P; i += 1024) cnt += (__float_as_uint(sv[i]) >= cand) ? 1 : 0;
    cnt = wave_sum_i(cnt);
    if (lane == 0) scnt[wv] = cnt;
    __syncthreads();
    int tot = 0;
#pragma unroll
    for (int j = 0; j < 16; ++j) tot += scnt[j];   // broadcast reads, uniform
    if (tot >= k) u = cand;
    __syncthreads();
  }
  const float vk = __uint_as_float(u);
  int cgt = 0; float sgt = 0.f;
  for (int i = tid; i < P; i += 1024) {
    float v = sv[i];
    if (__float_as_uint(v) > u) { cgt += 1; sgt += v; }
  }
  cgt = wave_sum_i(cgt);
  sgt = wave_sum(sgt);
  if (lane == 0) { scnt[wv] = cgt; ssum[wv] = sgt; }
  __syncthreads();
  if (tid == 0) {
    int cg = 0; float sg = 0.f;
#pragma unroll
    for (int j = 0; j < 16; ++j) { cg += scnt[j]; sg += ssum[j]; }
    atomicAdd(loss_c_accum, sg + vk * (float)(k - cg));
  }
}

// ---------------- finalize ----------------
__global__ void finalize_kernel(const float* __restrict__ lla,
                                const float* __restrict__ lca,
                                const int* __restrict__ nt,
                                float* __restrict__ out)
{
  if (threadIdx.x == 0 && blockIdx.x == 0) {
    float N = (float)(*nt);
    out[0] = lla[0] / N;
    out[1] = lca[0] / N;
  }
}

extern "C" void kernel_launch(void* const* d_in, const int* in_sizes, int n_in,
                              void* d_out, int out_size, void* d_ws, size_t ws_size,
                              hipStream_t stream) {
  const float* loc_p   = (const float*)d_in[0];
  const float* class_p = (const float*)d_in[1];
  const float* priors  = (const float*)d_in[2];
  const float* gt_box  = (const float*)d_in[3];
  const int*   gt_cls  = (const int*)d_in[4];

  const int P = in_sizes[2] / 4;
  const int B = in_sizes[0] / (4 * P);
  const int C = (int)((long long)in_sizes[1] / ((long long)B * P));
  const int G = in_sizes[4] / B;
  const long long BP = (long long)B * P;

  char* w = (char*)d_ws;
  float* best_iou = (float*)w; w += BP * 4;
  int*   bst_gt   = (int*)w;   w += BP * 4;
  int*   cls_t    = (int*)w;   w += BP * 4;
  float* loss_gt  = (float*)w; w += BP * 4;
  char* zbase = w;                      // ---- zero-initialized region ----
  float* lla = (float*)w;  w += 4;
  float* lca = (float*)w;  w += 4;
  int*   ntot = (int*)w;   w += 4;
  w += 4;                               // pad -> 8-align gt_best
  unsigned long long* gt_best = (unsigned long long*)w; w += (size_t)B * G * 8;
  int* num_pos = (int*)w;  w += (size_t)B * 4;
  const size_t zbytes = (size_t)(w - zbase);

  hipMemsetAsync(zbase, 0, zbytes, stream);

  const int chunk = (P + SPLIT - 1) / SPLIT;
  match1_kernel<<<dim3(SPLIT, B), 256, 0, stream>>>(
      priors, gt_box, best_iou, bst_gt, gt_best, P, G, chunk);
  force_kernel<<<B, 64, 0, stream>>>(gt_best, best_iou, P, G);
  match3_kernel<<<dim3(SPLIT, B), 256, 0, stream>>>(
      priors, gt_box, gt_cls, loc_p, best_iou, bst_gt, cls_t,
      num_pos, lla, ntot, P, G, chunk);

  const long long nrows = BP;
  const int nblocks = (int)((nrows + CE_ROWS - 1) / CE_ROWS);
  ce_kernel<<<nblocks, CE_ROWS, 0, stream>>>(class_p, cls_t, loss_gt, lca, C, nrows);

  topk_kernel<<<B, 1024, (size_t)P * sizeof(float), stream>>>(
      loss_gt, num_pos, lca, P, 3);

  finalize_kernel<<<1, 1, 0, stream>>>(lla, lca, ntot, (float*)d_out);
}